// Round 6
// baseline (6179.589 us; speedup 1.0000x reference)
//
#include <hip/hip_runtime.h>

using f32x4  = __attribute__((ext_vector_type(4))) float;
using short8 = __attribute__((ext_vector_type(8))) short;

#define DEV __device__ __forceinline__
#define MFMA16(a, b, c) __builtin_amdgcn_mfma_f32_16x16x32_bf16(a, b, c, 0, 0, 0)

// B=32, CIN=1, NBINS=128, NFRAMES=256, NFILT=64 -> Hc=64, Wc=128
// context: [2048][8192] (row m = b*64+l, col f = c*128+w)
// DDEC=512, G=1536, T=64, NCLS=17
// ctxW layout: [b][n][l] = [32][1536][64] f32
// whh_t layout: [j][n] = [512][1536] f32 (transposed W_hh)

DEV unsigned short f2bf(float f) {
  unsigned int u = __float_as_uint(f);
  unsigned int r = (u + 0x7fffu + ((u >> 16) & 1u)) >> 16;
  return (unsigned short)r;
}
DEV float bf2f(unsigned short s) { return __uint_as_float(((unsigned int)s) << 16); }
DEV float sigm(float x) { return 1.0f / (1.0f + expf(-x)); }

// ---------------- K1: prep (split wih to bf16 hi/lo, transpose whh) -------------
__global__ __launch_bounds__(256) void k_prep(
    const float* __restrict__ wih, const float* __restrict__ whh,
    unsigned short* __restrict__ wih_hi, unsigned short* __restrict__ wih_lo,
    float* __restrict__ whh_t) {
  unsigned int i = blockIdx.x * 256u + threadIdx.x;
  if (i < 12582912u) {
    float w = wih[i];
    unsigned short h = f2bf(w);
    wih_hi[i] = h;
    wih_lo[i] = f2bf(w - bf2f(h));
  }
  if (i < 786432u) {
    unsigned int j = i / 1536u, n = i - j * 1536u;
    whh_t[i] = whh[n * 512u + j];  // coalesced write, scattered read (L2 absorbs)
  }
}

// ---------------- K2: conv 3x3 stride2 pad1 -> context (bf16 hi/lo) --------------
__global__ __launch_bounds__(128) void k_conv(
    const float* __restrict__ x, const float* __restrict__ cw,
    unsigned short* __restrict__ ctx_hi, unsigned short* __restrict__ ctx_lo) {
  __shared__ float w[576];
  int t = threadIdx.x;
  for (int i = t; i < 576; i += 128) w[i] = cw[i];
  int blk = blockIdx.x;  // b*64 + h
  int b = blk >> 6, h = blk & 63;
  const float* xb = x + (size_t)b * 32768;
  int wcol = t;
  float xv[3][3];
  int ih0 = 2 * h - 1, iw0 = 2 * wcol - 1;
#pragma unroll
  for (int kh = 0; kh < 3; kh++) {
    int ih = ih0 + kh;
#pragma unroll
    for (int kw = 0; kw < 3; kw++) {
      int iw = iw0 + kw;
      bool ok = (ih >= 0) && (ih < 128) && (iw >= 0) && (iw < 256);
      xv[kh][kw] = ok ? xb[ih * 256 + iw] : 0.f;
    }
  }
  __syncthreads();
  size_t base = (size_t)blk * 8192 + wcol;
  for (int c = 0; c < 64; c++) {
    const float* wc = &w[c * 9];
    float acc = 0.f;
#pragma unroll
    for (int kh = 0; kh < 3; kh++)
#pragma unroll
      for (int kw = 0; kw < 3; kw++) acc += xv[kh][kw] * wc[kh * 3 + kw];
    unsigned short hi = f2bf(acc);
    ctx_hi[base + c * 128] = hi;
    ctx_lo[base + c * 128] = f2bf(acc - bf2f(hi));
  }
}

// ---------------- K3: ctxW = context @ W_ih^T  (split-bf16, 3-term MFMA) ---------
__global__ __launch_bounds__(256) void k_gemm(
    const unsigned short* __restrict__ A_hi, const unsigned short* __restrict__ A_lo,
    const unsigned short* __restrict__ B_hi, const unsigned short* __restrict__ B_lo,
    float* __restrict__ ctxW) {
  __shared__ unsigned short Ah[128 * 32], Al[128 * 32], Bh[128 * 32], Bl[128 * 32];
  int tid = threadIdx.x;
  int m0 = blockIdx.x * 128, n0 = blockIdx.y * 128;
  int wave = tid >> 6, lane = tid & 63;
  int wm = wave >> 1, wn = wave & 1;
  const f32x4 zero4 = {0.f, 0.f, 0.f, 0.f};
  f32x4 acc[4][4];
  for (int mi = 0; mi < 4; mi++)
    for (int ni = 0; ni < 4; ni++) acc[mi][ni] = zero4;

  for (int k0 = 0; k0 < 8192; k0 += 32) {
    __syncthreads();
#pragma unroll
    for (int i = 0; i < 2; i++) {
      int c = tid + i * 256;
      int row = c >> 2, col = (c & 3) << 3;
      size_t ga = (size_t)(m0 + row) * 8192 + k0 + col;
      size_t gb = (size_t)(n0 + row) * 8192 + k0 + col;
      *(short8*)&Ah[row * 32 + col] = *(const short8*)&A_hi[ga];
      *(short8*)&Al[row * 32 + col] = *(const short8*)&A_lo[ga];
      *(short8*)&Bh[row * 32 + col] = *(const short8*)&B_hi[gb];
      *(short8*)&Bl[row * 32 + col] = *(const short8*)&B_lo[gb];
    }
    __syncthreads();
    int kc = (lane >> 4) * 8;
    short8 ah[4], al[4], bh[4], bl[4];
#pragma unroll
    for (int mi = 0; mi < 4; mi++) {
      int r = wm * 64 + mi * 16 + (lane & 15);
      ah[mi] = *(short8*)&Ah[r * 32 + kc];
      al[mi] = *(short8*)&Al[r * 32 + kc];
    }
#pragma unroll
    for (int ni = 0; ni < 4; ni++) {
      int r = wn * 64 + ni * 16 + (lane & 15);
      bh[ni] = *(short8*)&Bh[r * 32 + kc];
      bl[ni] = *(short8*)&Bl[r * 32 + kc];
    }
#pragma unroll
    for (int mi = 0; mi < 4; mi++)
#pragma unroll
      for (int ni = 0; ni < 4; ni++) {
        acc[mi][ni] = MFMA16(ah[mi], bh[ni], acc[mi][ni]);
        acc[mi][ni] = MFMA16(ah[mi], bl[ni], acc[mi][ni]);
        acc[mi][ni] = MFMA16(al[mi], bh[ni], acc[mi][ni]);
      }
  }
  // epilogue: ctxW[b][n][l], 4 consecutive l per f32x4 accumulator
#pragma unroll
  for (int mi = 0; mi < 4; mi++)
#pragma unroll
    for (int ni = 0; ni < 4; ni++) {
      int n = n0 + wn * 64 + ni * 16 + (lane & 15);
      int mb = m0 + wm * 64 + mi * 16 + (lane >> 4) * 4;
      int bb = mb >> 6, l = mb & 63;
      *(f32x4*)&ctxW[(size_t)(bb * 1536 + n) * 64 + l] = acc[mi][ni];
    }
}

// ---------------- K4: scan — 32 wgs, one batch per wg, ZERO cross-wg sync --------
__global__ __launch_bounds__(512) void k_scan(
    const float* __restrict__ ctxW, const float* __restrict__ whh_t,
    const float* __restrict__ kw, const float* __restrict__ bw,
    const float* __restrict__ ow, const float* __restrict__ ob,
    float* __restrict__ d_out) {
  __shared__ float h_lds[512];
  __shared__ float w_lds[64];
  __shared__ float kwb[512], bwb[512];
  __shared__ float part_k[8], part_b[8];
  __shared__ float obs[17];

  const int b = blockIdx.x;       // batch owned by this wg
  const int tid = threadIdx.x;    // hidden index owned by this thread
  const int wave = tid >> 6, lane = tid & 63;

  kwb[tid] = kw[tid];
  bwb[tid] = bw[tid];
  if (tid < 17) obs[tid] = ob[tid];
  h_lds[tid] = 0.f;
  float kappa = 0.f;              // tracked redundantly by threads 0..63
  const float* cW = ctxW + (size_t)b * 98304;  // 1536*64
  __syncthreads();

  for (int t = 0; t < 64; t++) {
    // ---- A: kappa/beta partial dots over h (full f32) ----
    float hv = h_lds[tid];
    float kp = hv * kwb[tid], bp = hv * bwb[tid];
#pragma unroll
    for (int m = 1; m < 64; m <<= 1) {
      kp += __shfl_xor(kp, m, 64);
      bp += __shfl_xor(bp, m, 64);
    }
    if (lane == 0) { part_k[wave] = kp; part_b[wave] = bp; }
    __syncthreads();
    // ---- B: attention weights (threads 0..63), write ws output ----
    if (tid < 64) {
      float ks = 0.f, bs = 0.f;
#pragma unroll
      for (int w = 0; w < 8; w++) { ks += part_k[w]; bs += part_b[w]; }
      kappa += ks;
      float beta = expf(bs);
      float d = kappa - (float)tid;
      float wv = expf(-beta * d * d);
      w_lds[tid] = wv;
      d_out[34816 + ((b << 6) + t) * 64 + tid] = wv;
    }
    __syncthreads();
    // ---- C: gx from ctxW[b] (f32x4 over l) ----
    float gx0 = 0.f, gx1 = 0.f, gx2 = 0.f;
    {
      const float* c0 = cW + (size_t)tid * 64;
#pragma unroll
      for (int lc = 0; lc < 16; lc++) {
        f32x4 w4 = *(const f32x4*)&w_lds[lc * 4];
        f32x4 v0 = *(const f32x4*)(c0 + lc * 4);
        f32x4 v1 = *(const f32x4*)(c0 + 32768 + lc * 4);
        f32x4 v2 = *(const f32x4*)(c0 + 65536 + lc * 4);
#pragma unroll
        for (int q = 0; q < 4; q++) {
          gx0 = fmaf(w4[q], v0[q], gx0);
          gx1 = fmaf(w4[q], v1[q], gx1);
          gx2 = fmaf(w4[q], v2[q], gx2);
        }
      }
    }
    // ---- D: gh = h @ W_hh^T, full-f32 coalesced matvec via whh_t[j][n] ----
    float gh0 = 0.f, gh1 = 0.f, gh2 = 0.f;
    {
      const float* wr = whh_t + tid;
#pragma unroll 8
      for (int j = 0; j < 512; j++) {
        float hj = h_lds[j];  // LDS broadcast
        gh0 = fmaf(hj, wr[0], gh0);
        gh1 = fmaf(hj, wr[512], gh1);
        gh2 = fmaf(hj, wr[1024], gh2);
        wr += 1536;
      }
    }
    // ---- E: GRU update (thread owns hidden index tid) ----
    float rr = sigm(gx0 + gh0);
    float zz = sigm(gx1 + gh1);
    float nn = tanhf(gx2 + rr * gh2);
    float h = (1.f - zz) * nn + zz * hv;
    __syncthreads();            // all reads of old h done
    h_lds[tid] = h;
    __syncthreads();
    // ---- F: out projection (17 outputs, 16 lanes each) ----
    if (tid < 272) {
      int k = tid >> 4, ln = tid & 15;
      const float* owr = ow + k * 512;
      float s = 0.f;
#pragma unroll 8
      for (int q = 0; q < 32; q++) s += h_lds[ln + q * 16] * owr[ln + q * 16];
#pragma unroll
      for (int m = 1; m < 16; m <<= 1) s += __shfl_xor(s, m, 64);
      if (ln == 0) d_out[((b << 6) + t) * 17 + k] = s + obs[k];
    }
  }
}

// ---------------- launch ----------------
extern "C" void kernel_launch(void* const* d_in, const int* in_sizes, int n_in,
                              void* d_out, int out_size, void* d_ws, size_t ws_size,
                              hipStream_t stream) {
  (void)in_sizes; (void)n_in; (void)out_size; (void)ws_size;
  const float* x   = (const float*)d_in[0];
  const float* cw  = (const float*)d_in[2];
  const float* kw  = (const float*)d_in[3];
  const float* bw  = (const float*)d_in[4];
  const float* wih = (const float*)d_in[5];
  const float* whh = (const float*)d_in[6];
  const float* ow  = (const float*)d_in[7];
  const float* ob  = (const float*)d_in[8];
  float* out = (float*)d_out;
  char* ws = (char*)d_ws;

  unsigned short* ctx_hi = (unsigned short*)(ws);
  unsigned short* ctx_lo = (unsigned short*)(ws + 33554432);
  unsigned short* wih_hi = (unsigned short*)(ws + 67108864);
  unsigned short* wih_lo = (unsigned short*)(ws + 92274688);
  float*          whh_t  = (float*)(ws + 117440512);  // [512][1536] f32
  float*          ctxW   = (float*)(ws + 120586240);  // [32][1536][64] f32

  k_prep<<<49152, 256, 0, stream>>>(wih, whh, wih_hi, wih_lo, whh_t);
  k_conv<<<2048, 128, 0, stream>>>(x, cw, ctx_hi, ctx_lo);
  k_gemm<<<dim3(16, 12), 256, 0, stream>>>(ctx_hi, ctx_lo, wih_hi, wih_lo, ctxW);
  k_scan<<<32, 512, 0, stream>>>(ctxW, whh_t, kw, bw, ow, ob, out);
}

// Round 7
// 1416.644 us; speedup vs baseline: 4.3621x; 4.3621x over previous
//
#include <hip/hip_runtime.h>

using f32x4  = __attribute__((ext_vector_type(4))) float;
using short8 = __attribute__((ext_vector_type(8))) short;
using u32x4  = __attribute__((ext_vector_type(4))) unsigned int;

#define DEV __device__ __forceinline__
#define MFMA16(a, b, c) __builtin_amdgcn_mfma_f32_16x16x32_bf16(a, b, c, 0, 0, 0)

// B=32, CIN=1, NBINS=128, NFRAMES=256, NFILT=64 -> Hc=64, Wc=128
// DDEC=512, G=1536, T=64, NCLS=17, NWG=32
// ctxW: [b][n][l] = [32][1536][64] f32
// hbuf: [65][32][512] u32 (bf16 hi<<16|lo packed h), per-step fresh regions
// flags: [65][32][16] int (padded, 1 line per wg per step)

DEV unsigned short f2bf(float f) {
  unsigned int u = __float_as_uint(f);
  unsigned int r = (u + 0x7fffu + ((u >> 16) & 1u)) >> 16;
  return (unsigned short)r;
}
DEV float bf2f(unsigned short s) { return __uint_as_float(((unsigned int)s) << 16); }
DEV float sigm(float x) { return 1.0f / (1.0f + expf(-x)); }

// ---------------- K1: prep (split weights to bf16 hi/lo) ------------------------
__global__ __launch_bounds__(256) void k_prep(
    const float* __restrict__ wih, const float* __restrict__ whh,
    unsigned short* __restrict__ wih_hi, unsigned short* __restrict__ wih_lo,
    unsigned short* __restrict__ whh_hi, unsigned short* __restrict__ whh_lo) {
  unsigned int i = blockIdx.x * 256u + threadIdx.x;
  if (i < 12582912u) {
    float w = wih[i];
    unsigned short h = f2bf(w);
    wih_hi[i] = h;
    wih_lo[i] = f2bf(w - bf2f(h));
  }
  if (i < 786432u) {
    float w = whh[i];
    unsigned short h = f2bf(w);
    whh_hi[i] = h;
    whh_lo[i] = f2bf(w - bf2f(h));
  }
}

// ---------------- K2: conv 3x3 stride2 pad1 -> context (bf16 hi/lo) --------------
__global__ __launch_bounds__(128) void k_conv(
    const float* __restrict__ x, const float* __restrict__ cw,
    unsigned short* __restrict__ ctx_hi, unsigned short* __restrict__ ctx_lo) {
  __shared__ float w[576];
  int t = threadIdx.x;
  for (int i = t; i < 576; i += 128) w[i] = cw[i];
  int blk = blockIdx.x;  // b*64 + h
  int b = blk >> 6, h = blk & 63;
  const float* xb = x + (size_t)b * 32768;
  int wcol = t;
  float xv[3][3];
  int ih0 = 2 * h - 1, iw0 = 2 * wcol - 1;
#pragma unroll
  for (int kh = 0; kh < 3; kh++) {
    int ih = ih0 + kh;
#pragma unroll
    for (int kw = 0; kw < 3; kw++) {
      int iw = iw0 + kw;
      bool ok = (ih >= 0) && (ih < 128) && (iw >= 0) && (iw < 256);
      xv[kh][kw] = ok ? xb[ih * 256 + iw] : 0.f;
    }
  }
  __syncthreads();
  size_t base = (size_t)blk * 8192 + wcol;
  for (int c = 0; c < 64; c++) {
    const float* wc = &w[c * 9];
    float acc = 0.f;
#pragma unroll
    for (int kh = 0; kh < 3; kh++)
#pragma unroll
      for (int kw = 0; kw < 3; kw++) acc += xv[kh][kw] * wc[kh * 3 + kw];
    unsigned short hi = f2bf(acc);
    ctx_hi[base + c * 128] = hi;
    ctx_lo[base + c * 128] = f2bf(acc - bf2f(hi));
  }
}

// ---------------- K3: ctxW = context @ W_ih^T  (split-bf16, 3-term MFMA) ---------
__global__ __launch_bounds__(256) void k_gemm(
    const unsigned short* __restrict__ A_hi, const unsigned short* __restrict__ A_lo,
    const unsigned short* __restrict__ B_hi, const unsigned short* __restrict__ B_lo,
    float* __restrict__ ctxW) {
  __shared__ unsigned short Ah[128 * 32], Al[128 * 32], Bh[128 * 32], Bl[128 * 32];
  int tid = threadIdx.x;
  int m0 = blockIdx.x * 128, n0 = blockIdx.y * 128;
  int wave = tid >> 6, lane = tid & 63;
  int wm = wave >> 1, wn = wave & 1;
  const f32x4 zero4 = {0.f, 0.f, 0.f, 0.f};
  f32x4 acc[4][4];
  for (int mi = 0; mi < 4; mi++)
    for (int ni = 0; ni < 4; ni++) acc[mi][ni] = zero4;

  for (int k0 = 0; k0 < 8192; k0 += 32) {
    __syncthreads();
#pragma unroll
    for (int i = 0; i < 2; i++) {
      int c = tid + i * 256;
      int row = c >> 2, col = (c & 3) << 3;
      size_t ga = (size_t)(m0 + row) * 8192 + k0 + col;
      size_t gb = (size_t)(n0 + row) * 8192 + k0 + col;
      *(short8*)&Ah[row * 32 + col] = *(const short8*)&A_hi[ga];
      *(short8*)&Al[row * 32 + col] = *(const short8*)&A_lo[ga];
      *(short8*)&Bh[row * 32 + col] = *(const short8*)&B_hi[gb];
      *(short8*)&Bl[row * 32 + col] = *(const short8*)&B_lo[gb];
    }
    __syncthreads();
    int kc = (lane >> 4) * 8;
    short8 ah[4], al[4], bh[4], bl[4];
#pragma unroll
    for (int mi = 0; mi < 4; mi++) {
      int r = wm * 64 + mi * 16 + (lane & 15);
      ah[mi] = *(short8*)&Ah[r * 32 + kc];
      al[mi] = *(short8*)&Al[r * 32 + kc];
    }
#pragma unroll
    for (int ni = 0; ni < 4; ni++) {
      int r = wn * 64 + ni * 16 + (lane & 15);
      bh[ni] = *(short8*)&Bh[r * 32 + kc];
      bl[ni] = *(short8*)&Bl[r * 32 + kc];
    }
#pragma unroll
    for (int mi = 0; mi < 4; mi++)
#pragma unroll
      for (int ni = 0; ni < 4; ni++) {
        acc[mi][ni] = MFMA16(ah[mi], bh[ni], acc[mi][ni]);
        acc[mi][ni] = MFMA16(ah[mi], bl[ni], acc[mi][ni]);
        acc[mi][ni] = MFMA16(al[mi], bh[ni], acc[mi][ni]);
      }
  }
  // epilogue: ctxW[b][n][l], 4 consecutive l per f32x4 accumulator
#pragma unroll
  for (int mi = 0; mi < 4; mi++)
#pragma unroll
    for (int ni = 0; ni < 4; ni++) {
      int n = n0 + wn * 64 + ni * 16 + (lane & 15);
      int mb = m0 + wm * 64 + mi * 16 + (lane >> 4) * 4;
      int bb = mb >> 6, l = mb & 63;
      *(f32x4*)&ctxW[(size_t)(bb * 1536 + n) * 64 + l] = acc[mi][ni];
    }
}

// ---------------- K3b: init scan state (runs after k_gemm; overlays dead region) -
__global__ __launch_bounds__(256) void k_init(
    unsigned int* __restrict__ hbuf, int* __restrict__ flags) {
  int i = blockIdx.x * 256 + threadIdx.x;
  if (i < 16384) hbuf[i] = 0u;                       // h0 = 0 (step-0 region)
  if (i < 33280) flags[i] = (i < 512 && (i & 15) == 0) ? 1 : 0;  // step0 ready
}

// ---------------- K4: scan — 32 wgs hidden-sliced, flagged plain-load exchange ---
#define NWG 32

__global__ __launch_bounds__(512) void k_scan(
    const float* __restrict__ ctxW,
    const unsigned short* __restrict__ whh_hi, const unsigned short* __restrict__ whh_lo,
    const float* __restrict__ kw, const float* __restrict__ bw,
    const float* __restrict__ ow,
    unsigned int* __restrict__ hbuf, int* __restrict__ flags,
    float* __restrict__ pout, float* __restrict__ d_out) {
  __shared__ unsigned int h_lds[32 * 512];  // packed u32, 16B-XOR-swizzled rows
  __shared__ float ws_lds[32][64];
  __shared__ float gh_lds[32][48];
  __shared__ float hnew_lds[32][16];
  __shared__ float kwb[512], bwb[512];
  __shared__ float kappa_l[32], beta_l[32];
  __shared__ int w0_l[32];

  const int g = blockIdx.x;
  const int tid = threadIdx.x;
  const int b = tid >> 4, jj = tid & 15;
  const int wave = tid >> 6, lane = tid & 63;
  const int j0 = g * 16;
  const int sw_b = (b & 7) << 4;
  float h_prev = 0.f;

  kwb[tid] = kw[tid];
  bwb[tid] = bw[tid];
  if (tid < 32) kappa_l[tid] = 0.f;
  __syncthreads();

  for (int t = 0; t < 64; t++) {
    // ---- poll per-wg flags for step t (relaxed; no acquire -> no L2 invalidate) -
    if (tid < 32) {
      const int* fp = flags + t * 512 + tid * 16;
      while (__hip_atomic_load(fp, __ATOMIC_RELAXED, __HIP_MEMORY_SCOPE_AGENT) == 0)
        __builtin_amdgcn_s_sleep(1);
    }
    __syncthreads();
    asm volatile("" ::: "memory");
    // ---- Phase A: bulk plain load of fresh hbuf[t] + fused kappa/beta ----
    {
      const u32x4* src = (const u32x4*)(hbuf + t * 16384 + b * 512 + jj * 32);
      float kd = 0.f, bd = 0.f;
#pragma unroll
      for (int q = 0; q < 8; q++) {
        u32x4 v = src[q];
        int ob = (jj * 32 + q * 4) * 4;  // byte offset in row, 16B-aligned
        *(u32x4*)((char*)h_lds + b * 2048 + (ob ^ sw_b)) = v;
#pragma unroll
        for (int e = 0; e < 4; e++) {
          unsigned int u = v[e];
          float hv = __uint_as_float(u & 0xffff0000u) + __uint_as_float(u << 16);
          int j = jj * 32 + q * 4 + e;
          kd = fmaf(hv, kwb[j], kd);
          bd = fmaf(hv, bwb[j], bd);
        }
      }
#pragma unroll
      for (int mm = 1; mm < 16; mm <<= 1) {
        kd += __shfl_xor(kd, mm, 64);
        bd += __shfl_xor(bd, mm, 64);
      }
      if (jj == 0) {
        kappa_l[b] += kd;
        beta_l[b] = expf(bd);
      }
    }
    __syncthreads();
    // ---- Phase B: attention weights (full 64 for output) + gx window start ----
    if (tid < 32) {
      int w0 = ((int)roundf(kappa_l[tid]) - 14) & ~3;
      w0_l[tid] = w0 < 0 ? 0 : (w0 > 32 ? 32 : w0);
    }
#pragma unroll
    for (int p = 0; p < 4; p++) {
      int i = tid + p * 512;
      int bb = i >> 6, l = i & 63;
      float d = kappa_l[bb] - (float)l;
      float wv = expf(-beta_l[bb] * d * d);
      ws_lds[bb][l] = wv;
      if (bb == g) d_out[34816 + ((bb << 6) + t) * 64 + l] = wv;
    }
    __syncthreads();
    // ---- Phase C: gh MFMA (waves 0..5); waves 6-7 fall through to gx ----
    if (wave < 6) {
      int mt = wave & 1, nt = wave >> 1;
      int ar = mt * 16 + (lane & 15);                // batch row
      int n_g = nt * 512 + j0 + (lane & 15);         // global gate-row
      int sw = (ar & 7) << 4;
      const char* arow_p = (const char*)h_lds + ar * 2048;
      f32x4 acc = {0.f, 0.f, 0.f, 0.f};
      for (int ks = 0; ks < 16; ks++) {
        int ob = ks * 128 + (lane >> 4) * 32;
        u32x4 v1 = *(const u32x4*)(arow_p + (ob ^ sw));
        u32x4 v2 = *(const u32x4*)(arow_p + ((ob + 16) ^ sw));
        short8 ah, al;
#pragma unroll
        for (int q = 0; q < 4; q++) {
          ah[q] = (short)(v1[q] >> 16);
          al[q] = (short)(v1[q] & 0xffffu);
          ah[4 + q] = (short)(v2[q] >> 16);
          al[4 + q] = (short)(v2[q] & 0xffffu);
        }
        int kc = ks * 32 + (lane >> 4) * 8;
        short8 bh = *(const short8*)&whh_hi[(size_t)n_g * 512 + kc];
        short8 bl = *(const short8*)&whh_lo[(size_t)n_g * 512 + kc];
        acc = MFMA16(ah, bh, acc);
        acc = MFMA16(ah, bl, acc);
        acc = MFMA16(al, bh, acc);
      }
#pragma unroll
      for (int r = 0; r < 4; r++)
        gh_lds[mt * 16 + (lane >> 4) * 4 + r][nt * 16 + (lane & 15)] = acc[r];
    }
    // ---- Phase D: gx over 32-wide window around kappa (covers |d|<=14) ----
    float gx0 = 0.f, gx1 = 0.f, gx2 = 0.f;
    {
      int w0 = w0_l[b];
      const float* cb = ctxW + (size_t)(b * 1536 + j0 + jj) * 64 + w0;
#pragma unroll
      for (int lc = 0; lc < 8; lc++) {
        f32x4 w4 = *(const f32x4*)&ws_lds[b][w0 + lc * 4];
        f32x4 v0 = *(const f32x4*)(cb + lc * 4);
        f32x4 v1 = *(const f32x4*)(cb + 32768 + lc * 4);
        f32x4 v2 = *(const f32x4*)(cb + 65536 + lc * 4);
#pragma unroll
        for (int q = 0; q < 4; q++) {
          gx0 = fmaf(w4[q], v0[q], gx0);
          gx1 = fmaf(w4[q], v1[q], gx1);
          gx2 = fmaf(w4[q], v2[q], gx2);
        }
      }
    }
    __syncthreads();
    // ---- Phase E: gates + hidden update + publish h (relaxed atomics) ----
    {
      float rr = sigm(gx0 + gh_lds[b][jj]);
      float zz = sigm(gx1 + gh_lds[b][16 + jj]);
      float nn = tanhf(gx2 + rr * gh_lds[b][32 + jj]);
      float h = (1.f - zz) * nn + zz * h_prev;
      h_prev = h;
      hnew_lds[b][jj] = h;
      unsigned short hh = f2bf(h);
      unsigned short hl = f2bf(h - bf2f(hh));
      __hip_atomic_store(&hbuf[(t + 1) * 16384 + b * 512 + j0 + jj],
                         ((unsigned int)hh << 16) | (unsigned int)hl,
                         __ATOMIC_RELAXED, __HIP_MEMORY_SCOPE_AGENT);
    }
    __syncthreads();  // drains all waves' vmcnt -> wg's h stores are at L3
    if (tid == 0)
      __hip_atomic_store(&flags[(t + 1) * 512 + g * 16], 1,
                         __ATOMIC_RELAXED, __HIP_MEMORY_SCOPE_AGENT);
    // ---- Phase F: out-projection partials (off critical path) ----
    for (int i = tid; i < 544; i += 512) {
      int bo = i / 17, k = i - bo * 17;
      const float* owr = ow + k * 512 + j0;
      float s = 0.f;
#pragma unroll
      for (int j = 0; j < 16; j++) s += hnew_lds[bo][j] * owr[j];
      pout[((t * 32 + g) * 32 + bo) * 17 + k] = s;
    }
  }
}

// ---------------- K5: reduce pout over wgs + bias -> d_out ----------------------
__global__ __launch_bounds__(256) void k_fin(
    const float* __restrict__ pout, const float* __restrict__ ob,
    float* __restrict__ d_out) {
  int i = blockIdx.x * 256 + threadIdx.x;
  if (i >= 34816) return;
  int k = i % 17;
  int bt = i / 17;
  int b = bt >> 6, t = bt & 63;
  float s = ob[k];
#pragma unroll 8
  for (int g = 0; g < 32; g++) s += pout[((t * 32 + g) * 32 + b) * 17 + k];
  d_out[i] = s;
}

// ---------------- launch ----------------
extern "C" void kernel_launch(void* const* d_in, const int* in_sizes, int n_in,
                              void* d_out, int out_size, void* d_ws, size_t ws_size,
                              hipStream_t stream) {
  (void)in_sizes; (void)n_in; (void)out_size; (void)ws_size;
  const float* x   = (const float*)d_in[0];
  const float* cw  = (const float*)d_in[2];
  const float* kw  = (const float*)d_in[3];
  const float* bw  = (const float*)d_in[4];
  const float* wih = (const float*)d_in[5];
  const float* whh = (const float*)d_in[6];
  const float* ow  = (const float*)d_in[7];
  const float* ob  = (const float*)d_in[8];
  float* out = (float*)d_out;
  char* ws = (char*)d_ws;

  unsigned short* ctx_hi = (unsigned short*)(ws);
  unsigned short* ctx_lo = (unsigned short*)(ws + 33554432);
  unsigned short* wih_hi = (unsigned short*)(ws + 67108864);
  unsigned short* wih_lo = (unsigned short*)(ws + 92274688);
  unsigned short* whh_hi = (unsigned short*)(ws + 117440512);
  unsigned short* whh_lo = (unsigned short*)(ws + 119013376);
  float*          ctxW   = (float*)(ws + 120586240);       // [32][1536][64] f32
  // overlays (dead after k_gemm):
  float*          pout   = (float*)(ws);                   // [64][32][32][17] f32
  unsigned int*   hbuf   = (unsigned int*)(ws + 67108864); // [65][16384] u32
  int*            flags  = (int*)(ws + 71368704);          // [65][32][16] int

  k_prep<<<49152, 256, 0, stream>>>(wih, whh, wih_hi, wih_lo, whh_hi, whh_lo);
  k_conv<<<2048, 128, 0, stream>>>(x, cw, ctx_hi, ctx_lo);
  k_gemm<<<dim3(16, 12), 256, 0, stream>>>(ctx_hi, ctx_lo, wih_hi, wih_lo, ctxW);
  k_init<<<130, 256, 0, stream>>>(hbuf, flags);
  k_scan<<<NWG, 512, 0, stream>>>(ctxW, whh_hi, whh_lo, kw, bw, ow,
                                  hbuf, flags, pout, out);
  k_fin<<<136, 256, 0, stream>>>(pout, ob, out);
}

// Round 8
// 637.721 us; speedup vs baseline: 9.6901x; 2.2214x over previous
//
#include <hip/hip_runtime.h>

using f32x4  = __attribute__((ext_vector_type(4))) float;
using short8 = __attribute__((ext_vector_type(8))) short;
using u32x4  = __attribute__((ext_vector_type(4))) unsigned int;

#define DEV __device__ __forceinline__
#define MFMA16(a, b, c) __builtin_amdgcn_mfma_f32_16x16x32_bf16(a, b, c, 0, 0, 0)

// B=32, CIN=1, NBINS=128, NFRAMES=256, NFILT=64 -> Hc=64, Wc=128
// DDEC=512, G=1536, T=64, NCLS=17
// ctxW: [b][n][l] = [32][1536][64] f32
// Scan: 128 wgs = 4 batch-groups (8 b) x 32 j-slices (16 j).
// hbuf: [65][32][512] u32 (bf16 hi<<16|lo h), per-step fresh; flags [65][4][32][16]

DEV unsigned short f2bf(float f) {
  unsigned int u = __float_as_uint(f);
  unsigned int r = (u + 0x7fffu + ((u >> 16) & 1u)) >> 16;
  return (unsigned short)r;
}
DEV float bf2f(unsigned short s) { return __uint_as_float(((unsigned int)s) << 16); }
DEV float sigm(float x) { return 1.0f / (1.0f + expf(-x)); }

// ---------------- K1: prep (split wih to bf16 hi/lo) ----------------------------
__global__ __launch_bounds__(256) void k_prep(
    const float* __restrict__ wih,
    unsigned short* __restrict__ wih_hi, unsigned short* __restrict__ wih_lo) {
  unsigned int i = blockIdx.x * 256u + threadIdx.x;
  if (i < 12582912u) {
    float w = wih[i];
    unsigned short h = f2bf(w);
    wih_hi[i] = h;
    wih_lo[i] = f2bf(w - bf2f(h));
  }
}

// ---------------- K2: conv 3x3 stride2 pad1 -> context (bf16 hi/lo) --------------
__global__ __launch_bounds__(128) void k_conv(
    const float* __restrict__ x, const float* __restrict__ cw,
    unsigned short* __restrict__ ctx_hi, unsigned short* __restrict__ ctx_lo) {
  __shared__ float w[576];
  int t = threadIdx.x;
  for (int i = t; i < 576; i += 128) w[i] = cw[i];
  int blk = blockIdx.x;  // b*64 + h
  int b = blk >> 6, h = blk & 63;
  const float* xb = x + (size_t)b * 32768;
  int wcol = t;
  float xv[3][3];
  int ih0 = 2 * h - 1, iw0 = 2 * wcol - 1;
#pragma unroll
  for (int kh = 0; kh < 3; kh++) {
    int ih = ih0 + kh;
#pragma unroll
    for (int kw = 0; kw < 3; kw++) {
      int iw = iw0 + kw;
      bool ok = (ih >= 0) && (ih < 128) && (iw >= 0) && (iw < 256);
      xv[kh][kw] = ok ? xb[ih * 256 + iw] : 0.f;
    }
  }
  __syncthreads();
  size_t base = (size_t)blk * 8192 + wcol;
  for (int c = 0; c < 64; c++) {
    const float* wc = &w[c * 9];
    float acc = 0.f;
#pragma unroll
    for (int kh = 0; kh < 3; kh++)
#pragma unroll
      for (int kw = 0; kw < 3; kw++) acc += xv[kh][kw] * wc[kh * 3 + kw];
    unsigned short hi = f2bf(acc);
    ctx_hi[base + c * 128] = hi;
    ctx_lo[base + c * 128] = f2bf(acc - bf2f(hi));
  }
}

// ---------------- K3: ctxW = context @ W_ih^T  (split-bf16, 3-term MFMA) ---------
__global__ __launch_bounds__(256) void k_gemm(
    const unsigned short* __restrict__ A_hi, const unsigned short* __restrict__ A_lo,
    const unsigned short* __restrict__ B_hi, const unsigned short* __restrict__ B_lo,
    float* __restrict__ ctxW) {
  __shared__ unsigned short Ah[128 * 32], Al[128 * 32], Bh[128 * 32], Bl[128 * 32];
  int tid = threadIdx.x;
  int m0 = blockIdx.x * 128, n0 = blockIdx.y * 128;
  int wave = tid >> 6, lane = tid & 63;
  int wm = wave >> 1, wn = wave & 1;
  const f32x4 zero4 = {0.f, 0.f, 0.f, 0.f};
  f32x4 acc[4][4];
  for (int mi = 0; mi < 4; mi++)
    for (int ni = 0; ni < 4; ni++) acc[mi][ni] = zero4;

  for (int k0 = 0; k0 < 8192; k0 += 32) {
    __syncthreads();
#pragma unroll
    for (int i = 0; i < 2; i++) {
      int c = tid + i * 256;
      int row = c >> 2, col = (c & 3) << 3;
      size_t ga = (size_t)(m0 + row) * 8192 + k0 + col;
      size_t gb = (size_t)(n0 + row) * 8192 + k0 + col;
      *(short8*)&Ah[row * 32 + col] = *(const short8*)&A_hi[ga];
      *(short8*)&Al[row * 32 + col] = *(const short8*)&A_lo[ga];
      *(short8*)&Bh[row * 32 + col] = *(const short8*)&B_hi[gb];
      *(short8*)&Bl[row * 32 + col] = *(const short8*)&B_lo[gb];
    }
    __syncthreads();
    int kc = (lane >> 4) * 8;
    short8 ah[4], al[4], bh[4], bl[4];
#pragma unroll
    for (int mi = 0; mi < 4; mi++) {
      int r = wm * 64 + mi * 16 + (lane & 15);
      ah[mi] = *(short8*)&Ah[r * 32 + kc];
      al[mi] = *(short8*)&Al[r * 32 + kc];
    }
#pragma unroll
    for (int ni = 0; ni < 4; ni++) {
      int r = wn * 64 + ni * 16 + (lane & 15);
      bh[ni] = *(short8*)&Bh[r * 32 + kc];
      bl[ni] = *(short8*)&Bl[r * 32 + kc];
    }
#pragma unroll
    for (int mi = 0; mi < 4; mi++)
#pragma unroll
      for (int ni = 0; ni < 4; ni++) {
        acc[mi][ni] = MFMA16(ah[mi], bh[ni], acc[mi][ni]);
        acc[mi][ni] = MFMA16(ah[mi], bl[ni], acc[mi][ni]);
        acc[mi][ni] = MFMA16(al[mi], bh[ni], acc[mi][ni]);
      }
  }
#pragma unroll
  for (int mi = 0; mi < 4; mi++)
#pragma unroll
    for (int ni = 0; ni < 4; ni++) {
      int n = n0 + wn * 64 + ni * 16 + (lane & 15);
      int mb = m0 + wm * 64 + mi * 16 + (lane >> 4) * 4;
      int bb = mb >> 6, l = mb & 63;
      *(f32x4*)&ctxW[(size_t)(bb * 1536 + n) * 64 + l] = acc[mi][ni];
    }
}

// ---------------- K3b: init scan state (overlays dead wih_hi region) -------------
__global__ __launch_bounds__(256) void k_init(
    unsigned int* __restrict__ hbuf, int* __restrict__ flags) {
  int i = blockIdx.x * 256 + threadIdx.x;
  if (i < 16384) hbuf[i] = 0u;                    // h0 = 0
  if (i < 133120) flags[i] = (i < 2048 && (i & 15) == 0) ? 1 : 0;  // step0 ready
}

// ---------------- K4: scan — 128 wgs (4 bg x 32 j-slices), LDS-resident W_hh -----
__global__ __launch_bounds__(512) void k_scan(
    const float* __restrict__ ctxW, const float* __restrict__ whh,
    const float* __restrict__ kw, const float* __restrict__ bw,
    const float* __restrict__ ow, const float* __restrict__ ob,
    unsigned int* __restrict__ hbuf, int* __restrict__ flags,
    float* __restrict__ d_out) {
  __shared__ unsigned short whh_h[48 * 512], whh_l[48 * 512];  // swizzled
  __shared__ unsigned short h_h[9 * 512], h_l[9 * 512];        // row 8 = zeros
  __shared__ float ws_lds[8][64];
  __shared__ float gh_lds[16][48];
  __shared__ float kwb[512], bwb[512];
  __shared__ float kappa_l[8], beta_l[8];
  __shared__ int   w0_l[8];
  __shared__ float obs[17];

  const int wg = blockIdx.x;
  const int g = wg & 31, bg = wg >> 5;
  const int j0 = g * 16;
  const int tid = threadIdx.x;
  const int wave = tid >> 6, lane = tid & 63;
  float h_prev = 0.f;  // owned (b,jj) for waves 6-7
  float gx0 = 0.f, gx1 = 0.f, gx2 = 0.f;

  kwb[tid] = kw[tid];
  bwb[tid] = bw[tid];
  if (tid < 17) obs[tid] = ob[tid];
  if (tid < 8) kappa_l[tid] = 0.f;
  *(unsigned short*)((char*)h_h + 8 * 1024 + tid * 2) = 0;  // zero pad row
  *(unsigned short*)((char*)h_l + 8 * 1024 + tid * 2) = 0;
  // stage W_hh slice (48 rows x 512) -> LDS bf16 hi/lo, swizzled
#pragma unroll 4
  for (int r = 0; r < 48; r++) {
    int n_g = (r >> 4) * 512 + j0 + (r & 15);
    float w = whh[n_g * 512 + tid];
    unsigned short hi = f2bf(w);
    unsigned short lo = f2bf(w - bf2f(hi));
    int byte = (r * 1024 + tid * 2) ^ ((r & 7) << 4);
    *(unsigned short*)((char*)whh_h + byte) = hi;
    *(unsigned short*)((char*)whh_l + byte) = lo;
  }
  __syncthreads();

  for (int t = 0; t < 64; t++) {
    // ---- poll: all 32 wgs of this batch-group published step t ----
    if (tid < 32) {
      const int* fp = flags + ((t * 4 + bg) * 32 + tid) * 16;
      while (__hip_atomic_load(fp, __ATOMIC_RELAXED, __HIP_MEMORY_SCOPE_AGENT) == 0)
        __builtin_amdgcn_s_sleep(1);
    }
    __syncthreads();
    asm volatile("" ::: "memory");
    // ---- Phase A: wave w stages h row (b=w); fused kappa/beta (full dot) ----
    {
      const unsigned int* src = hbuf + t * 16384 + (bg * 8 + wave) * 512 + lane * 8;
      u32x4 v0 = *(const u32x4*)(src);
      u32x4 v1 = *(const u32x4*)(src + 4);
      short8 hsv, lsv;
      float kd = 0.f, bd = 0.f;
#pragma unroll
      for (int e = 0; e < 8; e++) {
        unsigned int u = (e < 4) ? v0[e] : v1[e - 4];
        hsv[e] = (short)(u >> 16);
        lsv[e] = (short)(u & 0xffffu);
        float hv = __uint_as_float(u & 0xffff0000u) + __uint_as_float(u << 16);
        int j = lane * 8 + e;
        kd = fmaf(hv, kwb[j], kd);
        bd = fmaf(hv, bwb[j], bd);
      }
      int byte = (wave * 1024 + lane * 16) ^ ((wave & 7) << 4);
      *(short8*)((char*)h_h + byte) = hsv;
      *(short8*)((char*)h_l + byte) = lsv;
#pragma unroll
      for (int mm = 1; mm < 64; mm <<= 1) {
        kd += __shfl_xor(kd, mm, 64);
        bd += __shfl_xor(bd, mm, 64);
      }
      if (lane == 0) {
        float kap = kappa_l[wave] + kd;
        kappa_l[wave] = kap;
        beta_l[wave] = expf(bd);
        int w0 = ((int)roundf(kap) - 14) & ~3;
        w0_l[wave] = w0 < 0 ? 0 : (w0 > 32 ? 32 : w0);
      }
    }
    __syncthreads();
    // ---- Phase B: attention weights (b=wave, l=lane); g in 8..15 writes out ----
    {
      float d = kappa_l[wave] - (float)lane;
      float wv = expf(-beta_l[wave] * d * d);
      ws_lds[wave][lane] = wv;
      if (g - 8 == wave)
        d_out[34816 + (((bg * 8 + wave) << 6) + t) * 64 + lane] = wv;
    }
    __syncthreads();
    // ---- Phase C (waves 0-2): gh MFMA from LDS  ||  Phase D (waves 6-7): gx ----
    if (wave < 3) {
      int nrow = wave * 16 + (lane & 15);
      int ar = lane & 15;
      int arow = ar < 8 ? ar : 8;  // rows 8-15 -> shared zero row
      int swb = (nrow & 7) << 4, swa = (arow & 7) << 4;
      f32x4 acc = {0.f, 0.f, 0.f, 0.f};
      for (int ks = 0; ks < 16; ks++) {
        int kb = ks * 64 + (lane >> 4) * 16;
        short8 ah = *(short8*)((char*)h_h + ((arow * 1024 + kb) ^ swa));
        short8 al = *(short8*)((char*)h_l + ((arow * 1024 + kb) ^ swa));
        short8 bh = *(short8*)((char*)whh_h + ((nrow * 1024 + kb) ^ swb));
        short8 bl = *(short8*)((char*)whh_l + ((nrow * 1024 + kb) ^ swb));
        acc = MFMA16(ah, bh, acc);
        acc = MFMA16(ah, bl, acc);
        acc = MFMA16(al, bh, acc);
      }
#pragma unroll
      for (int r = 0; r < 4; r++)
        gh_lds[(lane >> 4) * 4 + r][wave * 16 + (lane & 15)] = acc[r];
    } else if (wave >= 6) {
      int idx = tid - 384;          // 0..127
      int b = idx >> 4, jj = idx & 15;
      int w0 = w0_l[b];
      const float* cb = ctxW + (size_t)((bg * 8 + b) * 1536 + j0 + jj) * 64 + w0;
      gx0 = gx1 = gx2 = 0.f;
#pragma unroll
      for (int lc = 0; lc < 8; lc++) {
        f32x4 w4 = *(const f32x4*)&ws_lds[b][w0 + lc * 4];
        f32x4 c0 = *(const f32x4*)(cb + lc * 4);
        f32x4 c1 = *(const f32x4*)(cb + 32768 + lc * 4);
        f32x4 c2 = *(const f32x4*)(cb + 65536 + lc * 4);
#pragma unroll
        for (int q = 0; q < 4; q++) {
          gx0 = fmaf(w4[q], c0[q], gx0);
          gx1 = fmaf(w4[q], c1[q], gx1);
          gx2 = fmaf(w4[q], c2[q], gx2);
        }
      }
    }
    __syncthreads();
    // ---- Phase E (waves 6-7): gates + update + publish h ----
    if (wave >= 6) {
      int idx = tid - 384;
      int b = idx >> 4, jj = idx & 15;
      float rr = sigm(gx0 + gh_lds[b][jj]);
      float zz = sigm(gx1 + gh_lds[b][16 + jj]);
      float nn = tanhf(gx2 + rr * gh_lds[b][32 + jj]);
      float h = (1.f - zz) * nn + zz * h_prev;
      h_prev = h;
      unsigned short hh = f2bf(h);
      unsigned short hl = f2bf(h - bf2f(hh));
      __hip_atomic_store(&hbuf[(t + 1) * 16384 + (bg * 8 + b) * 512 + j0 + jj],
                         ((unsigned int)hh << 16) | (unsigned int)hl,
                         __ATOMIC_RELAXED, __HIP_MEMORY_SCOPE_AGENT);
    }
    __syncthreads();  // drain h stores
    if (tid == 0)
      __hip_atomic_store(&flags[(((t + 1) * 4 + bg) * 32 + g) * 16], 1,
                         __ATOMIC_RELAXED, __HIP_MEMORY_SCOPE_AGENT);
    // ---- Phase F (g<8, off critical path): out(t-1) for b = g from staged h_t ---
    if (g < 8 && t > 0 && tid < 272) {
      int k = tid >> 4, ln = tid & 15;
      float s = 0.f;
#pragma unroll 8
      for (int q = 0; q < 32; q++) {
        int j = ln + q * 16;
        int hb = (g * 1024 + j * 2) ^ ((g & 7) << 4);
        float hv = bf2f(*(const unsigned short*)((const char*)h_h + hb)) +
                   bf2f(*(const unsigned short*)((const char*)h_l + hb));
        s = fmaf(hv, ow[k * 512 + j], s);
      }
#pragma unroll
      for (int mm = 1; mm < 16; mm <<= 1) s += __shfl_xor(s, mm, 64);
      if (ln == 0)
        d_out[(((bg * 8 + g) << 6) + (t - 1)) * 17 + k] = s + obs[k];
    }
  }
  // ---- final out(63) from h_64 (g<8) ----
  if (g < 8) {
    if (tid < 32) {
      const int* fp = flags + ((64 * 4 + bg) * 32 + tid) * 16;
      while (__hip_atomic_load(fp, __ATOMIC_RELAXED, __HIP_MEMORY_SCOPE_AGENT) == 0)
        __builtin_amdgcn_s_sleep(1);
    }
    __syncthreads();
    asm volatile("" ::: "memory");
    {
      unsigned int u = hbuf[64 * 16384 + (bg * 8 + g) * 512 + tid];
      ((float*)ws_lds)[tid] =
          __uint_as_float(u & 0xffff0000u) + __uint_as_float(u << 16);
    }
    __syncthreads();
    if (tid < 272) {
      int k = tid >> 4, ln = tid & 15;
      float s = 0.f;
#pragma unroll 8
      for (int q = 0; q < 32; q++) {
        int j = ln + q * 16;
        s = fmaf(((const float*)ws_lds)[j], ow[k * 512 + j], s);
      }
#pragma unroll
      for (int mm = 1; mm < 16; mm <<= 1) s += __shfl_xor(s, mm, 64);
      if (ln == 0)
        d_out[(((bg * 8 + g) << 6) + 63) * 17 + k] = s + obs[k];
    }
  }
}

// ---------------- launch ----------------
extern "C" void kernel_launch(void* const* d_in, const int* in_sizes, int n_in,
                              void* d_out, int out_size, void* d_ws, size_t ws_size,
                              hipStream_t stream) {
  (void)in_sizes; (void)n_in; (void)out_size; (void)ws_size;
  const float* x   = (const float*)d_in[0];
  const float* cw  = (const float*)d_in[2];
  const float* kw  = (const float*)d_in[3];
  const float* bw  = (const float*)d_in[4];
  const float* wih = (const float*)d_in[5];
  const float* whh = (const float*)d_in[6];
  const float* ow  = (const float*)d_in[7];
  const float* ob  = (const float*)d_in[8];
  float* out = (float*)d_out;
  char* ws = (char*)d_ws;

  unsigned short* ctx_hi = (unsigned short*)(ws);
  unsigned short* ctx_lo = (unsigned short*)(ws + 33554432);
  unsigned short* wih_hi = (unsigned short*)(ws + 67108864);
  unsigned short* wih_lo = (unsigned short*)(ws + 92274688);
  float*          ctxW   = (float*)(ws + 120586240);       // [32][1536][64] f32
  // overlays (dead after k_gemm):
  unsigned int*   hbuf   = (unsigned int*)(ws + 67108864); // [65][16384] u32
  int*            flags  = (int*)(ws + 71368704);          // [65][4][32][16] int

  k_prep<<<49152, 256, 0, stream>>>(wih, wih_hi, wih_lo);
  k_conv<<<2048, 128, 0, stream>>>(x, cw, ctx_hi, ctx_lo);
  k_gemm<<<dim3(16, 12), 256, 0, stream>>>(ctx_hi, ctx_lo, wih_hi, wih_lo, ctxW);
  k_init<<<520, 256, 0, stream>>>(hbuf, flags);
  k_scan<<<128, 512, 0, stream>>>(ctxW, whh, kw, bw, ow, ob, hbuf, flags, out);
}